// Round 6
// baseline (73.082 us; speedup 1.0000x reference)
//
#include <hip/hip_runtime.h>

// Hamiltonian flow, separable H: dq/dt = p ; dp/dt = -(q + q^3), m(q)=q+q^3.
// Established law (R1,R2,R3,R5): runtime tracks dynamic packed-VALU instr
// count; ILP/occupancy changes are neutral at 2 waves/SIMD. R6: reduction
// tree sharing, 19 -> 18 pk ops/step:
//   qa = q + h p ; q2 = q + dt p
//   qb = qa - (dt^2/4) m1 ; qc = q2 - (dt^2/2) m2
//   a1 = m1+m4 ; a2 = m2+m3
//   p' = p  - (dt/6) (a1 + 2 a2)
//   q' = q2 - (dt^2/6)(m1 + a2)
// 262144 pairs -> 131072 threads (2 pairs packed per thread) -> 512x256.

typedef float v2f __attribute__((ext_vector_type(2)));

__device__ __forceinline__ v2f vfma(v2f a, v2f b, v2f c) {
    return __builtin_elementwise_fma(a, b, c);
}

__global__ __launch_bounds__(256) void HamiltonianFlow_23957327577411_kernel(
    const float4* __restrict__ x0, float4* __restrict__ out, int n2)
{
    int i = blockIdx.x * blockDim.x + threadIdx.x;
    if (i >= n2) return;

    float4 v = x0[i];
    v2f q = {v.x, v.z};   // component 0 = pair 0, component 1 = pair 1
    v2f p = {v.y, v.w};

    const float dt_s = (float)(10.0 / 255.0);
    const float h_s  = 0.5f * dt_s;

    const v2f dt   = {dt_s, dt_s};
    const v2f h    = {h_s, h_s};
    const v2f nc1  = {-dt_s * dt_s * 0.25f,        -dt_s * dt_s * 0.25f};        // -dt^2/4
    const v2f nc2  = {-dt_s * dt_s * 0.5f,         -dt_s * dt_s * 0.5f};         // -dt^2/2
    const v2f nc3  = {-dt_s * dt_s * (1.0f/6.0f),  -dt_s * dt_s * (1.0f/6.0f)};  // -dt^2/6
    const v2f ndt6 = {-dt_s * (1.0f/6.0f),         -dt_s * (1.0f/6.0f)};         // -dt/6
    const v2f two  = {2.0f, 2.0f};

    #pragma unroll 15
    for (int s = 0; s < 255; ++s) {
        v2f u1 = q * q;
        v2f m1 = vfma(u1, q, q);        // m(q)
        v2f qa = vfma(h,  p, q);        // q + h p
        v2f q2 = vfma(dt, p, q);        // q + dt p

        v2f u2 = qa * qa;
        v2f m2 = vfma(u2, qa, qa);      // m(qa)
        v2f qb = vfma(nc1, m1, qa);     // qa - (dt^2/4) m1

        v2f u3 = qb * qb;
        v2f m3 = vfma(u3, qb, qb);      // m(qb)
        v2f qc = vfma(nc2, m2, q2);     // q2 - (dt^2/2) m2

        v2f u4 = qc * qc;
        v2f m4 = vfma(u4, qc, qc);      // m(qc)

        v2f a1 = m1 + m4;
        v2f a2 = m2 + m3;

        // p' = p - dt/6 (a1 + 2 a2)
        v2f s3 = vfma(two, a2, a1);
        p = vfma(ndt6, s3, p);

        // q' = q2 - dt^2/6 (m1 + a2)
        v2f t2 = m1 + a2;
        q = vfma(nc3, t2, q2);
    }

    out[i] = make_float4(q.x, p.x, q.y, p.y);
}

extern "C" void kernel_launch(void* const* d_in, const int* in_sizes, int n_in,
                              void* d_out, int out_size, void* d_ws, size_t ws_size,
                              hipStream_t stream) {
    const float4* x0 = (const float4*)d_in[0];
    float4* out = (float4*)d_out;
    int n2 = in_sizes[0] / 4;           // 2 pairs (4 floats) per thread
    int block = 256;
    int grid = (n2 + block - 1) / block;
    HamiltonianFlow_23957327577411_kernel<<<grid, block, 0, stream>>>(x0, out, n2);
}